// Round 13
// baseline (242.478 us; speedup 1.0000x reference)
//
#include <hip/hip_runtime.h>

// NCN recurrence, 2 layers fused into ONE persistent kernel.
// B=4, N=4096, E=128, NK=4, ce=32, CACHE=32, m=128.
// 2048 independent [32x32] subproblems per layer; one WAVE per subproblem.
// Grid 256 blocks x 512 threads (8 waves/block, 1 block/CU co-resident ->
// device-scope atomic grid barrier between layers is deadlock-free).
//
// R13 = R10's fused structure (correct, replay-safe, VISIBLE in top-5) with
// the spill fixed: ALL state in named f32x2 vars (guaranteed mem2reg) +
// __launch_bounds__(512, 2) (VGPR cap 256; ~110 needed). R10 spilled
// (VGPR_Count=52 -> scratch round-trips, VALUBusy 15%).
// State kept pre-scaled: zi = L1*xi (L1=log2 e), weights stored as W/L1:
//   sim_true = dot(zi,Wi/L1) + dot(zj,Wj/L1); arg = zi + sim*zj  (2*L1*T)
//   -> saves 8 pk_mul/step vs scaling xi each step.
// tanh via 0.1F = 0.1 - 0.2/(exp2(arg)+1), unclamped (over/underflow -> +-1).
// Scan step: 16 bpermute zj pulls; u = dot16(zi,wi)+dot16(zj,wj);
// sim = u + shfl_xor(u,32)  (zj uniform per half => Wj term uniform).
// Barrier state in ws[0..511], zeroed by hipMemsetAsync -> idempotent launch.

namespace {
constexpr int kB = 4;
constexpr int kN = 4096;
constexpr int kE = 128;
constexpr int kCE = 32;          // E / NK
constexpr int kH  = 16;          // feats per lane
constexpr int kCache = 32;
constexpr int kM = kN / kCache;  // 128 groups per batch
constexpr int kBlocks = 256;
constexpr int kThreads = 512;    // 8 waves/block

typedef __attribute__((ext_vector_type(2))) float f32x2;

__device__ __forceinline__ f32x2 pk_fma(f32x2 a, f32x2 b, f32x2 c) {
    return __builtin_elementwise_fma(a, b, c);
}
__device__ __forceinline__ float bperm_f(int addr, float v) {
    return __int_as_float(__builtin_amdgcn_ds_bpermute(addr, __float_as_int(v)));
}
}  // namespace

// load 16 floats (4x float4) into 8 named f32x2, scaled by constant sc
#define LD16S(dst, ptr, sc)                                             \
    {                                                                   \
        const float4* p4 = reinterpret_cast<const float4*>(ptr);        \
        float4 q0 = p4[0], q1 = p4[1], q2 = p4[2], q3 = p4[3];          \
        dst##0 = f32x2{q0.x * sc, q0.y * sc};                           \
        dst##1 = f32x2{q0.z * sc, q0.w * sc};                           \
        dst##2 = f32x2{q1.x * sc, q1.y * sc};                           \
        dst##3 = f32x2{q1.z * sc, q1.w * sc};                           \
        dst##4 = f32x2{q2.x * sc, q2.y * sc};                           \
        dst##5 = f32x2{q2.z * sc, q2.w * sc};                           \
        dst##6 = f32x2{q3.x * sc, q3.y * sc};                           \
        dst##7 = f32x2{q3.z * sc, q3.w * sc};                           \
    }

// store 8 named f32x2 as 4x float4, scaled by constant sc
#define ST16S(src, ptr, sc)                                             \
    {                                                                   \
        float4* p4 = reinterpret_cast<float4*>(ptr);                    \
        p4[0] = float4{src##0 .x * sc, src##0 .y * sc,                  \
                       src##1 .x * sc, src##1 .y * sc};                 \
        p4[1] = float4{src##2 .x * sc, src##2 .y * sc,                  \
                       src##3 .x * sc, src##3 .y * sc};                 \
        p4[2] = float4{src##4 .x * sc, src##4 .y * sc,                  \
                       src##5 .x * sc, src##5 .y * sc};                 \
        p4[3] = float4{src##6 .x * sc, src##6 .y * sc,                  \
                       src##7 .x * sc, src##7 .y * sc};                 \
    }

#define PULL(q)                                                         \
    f32x2 zj##q;                                                        \
    zj##q .x = bperm_f(srcaddr, zi##q .x);                              \
    zj##q .y = bperm_f(srcaddr, zi##q .y);

#define UPD(q)                                                          \
    {                                                                   \
        f32x2 arg = pk_fma(zj##q, sv, zi##q);                           \
        f32x2 t2;                                                       \
        t2.x = __builtin_amdgcn_exp2f(arg.x);                           \
        t2.y = __builtin_amdgcn_exp2f(arg.y);                           \
        f32x2 den = t2 + one;                                           \
        f32x2 rc;                                                       \
        rc.x = __builtin_amdgcn_rcpf(den.x);                            \
        rc.y = __builtin_amdgcn_rcpf(den.y);                            \
        xa##q = pk_fma(m02, rc, pk_fma(c9, xa##q, c01));                \
        zi##q = pk_fma(cL1, xa##q, zi##q * c9);                         \
    }

// one layer's 32-step scan on the named state (zi/xa/wi/wj must be in scope)
#define SCAN_LAYER()                                                    \
    _Pragma("unroll 2")                                                 \
    for (int j = 0; j < kCache; ++j) {                                  \
        const int srcaddr = srcbase + j * 4;                            \
        PULL(0) PULL(1) PULL(2) PULL(3) PULL(4) PULL(5) PULL(6) PULL(7) \
        f32x2 A = zi0 * wi0;                                            \
        f32x2 Bv = zi1 * wi1;                                           \
        f32x2 C = zj0 * wj0;                                            \
        f32x2 D = zj1 * wj1;                                            \
        A  = pk_fma(zi2, wi2, A);  Bv = pk_fma(zi3, wi3, Bv);           \
        C  = pk_fma(zj2, wj2, C);  D  = pk_fma(zj3, wj3, D);            \
        A  = pk_fma(zi4, wi4, A);  Bv = pk_fma(zi5, wi5, Bv);           \
        C  = pk_fma(zj4, wj4, C);  D  = pk_fma(zj5, wj5, D);            \
        A  = pk_fma(zi6, wi6, A);  Bv = pk_fma(zi7, wi7, Bv);           \
        C  = pk_fma(zj6, wj6, C);  D  = pk_fma(zj7, wj7, D);            \
        f32x2 uv = (A + Bv) + (C + D);                                  \
        float u  = uv.x + uv.y;                                         \
        const float sim = u + __shfl_xor(u, 32, 64);                    \
        const f32x2 sv = {sim, sim};                                    \
        UPD(0) UPD(1) UPD(2) UPD(3) UPD(4) UPD(5) UPD(6) UPD(7)         \
    }

__global__ void __launch_bounds__(kThreads, 2) ncn_fused_kernel(
    const float* __restrict__ x_in, const float* __restrict__ xa_in,
    const float* __restrict__ W,    // 2 layers x 256 floats
    float* __restrict__ x_mid, float* __restrict__ xa_mid,
    float* __restrict__ x_out, float* __restrict__ xa_out,
    unsigned* __restrict__ bar_cnt, unsigned* __restrict__ bar_gen)
{
    const int tid  = threadIdx.x;
    const int wave = tid >> 6;
    const int lane = tid & 63;
    const int id   = blockIdx.x * 8 + wave;   // subproblem id, 0..2047
    const int n    = id & 3;
    const int g    = (id >> 2) & (kM - 1);
    const int b    = id >> 9;
    const int o    = lane & 31;
    const int h    = lane >> 5;

    constexpr float L1   = 1.4426950408889634f;   // log2(e)
    constexpr float iL1  = 0.6931471805599453f;   // 1/L1 = ln 2
    const f32x2 one = {1.0f, 1.0f};
    const f32x2 m02 = {-0.2f, -0.2f};
    const f32x2 c9  = {0.9f, 0.9f};
    const f32x2 c01 = {0.1f, 0.1f};
    const f32x2 cL1 = {0.1f * L1, 0.1f * L1};

    const int srcbase = (lane & 32) * 4;   // zj source lane = (lane&32) + j

    f32x2 zi0, zi1, zi2, zi3, zi4, zi5, zi6, zi7;
    f32x2 xa0, xa1, xa2, xa3, xa4, xa5, xa6, xa7;
    f32x2 wi0, wi1, wi2, wi3, wi4, wi5, wi6, wi7;
    f32x2 wj0, wj1, wj2, wj3, wj4, wj5, wj6, wj7;

    // ---- layer 0 (s = 0): row = g*32 + o ----
    const int r0 = (g << 5) + o;
    const size_t base0 = ((size_t)(b * kN + r0)) * kE + n * kCE + h * kH;

    LD16S(zi, x_in + base0, L1);
    LD16S(xa, xa_in + base0, 1.0f);
    LD16S(wi, W + n * kCE + h * kH, iL1);
    LD16S(wj, W + kE + n * kCE + h * kH, iL1);

    SCAN_LAYER();

    ST16S(zi, x_mid + base0, iL1);
    ST16S(xa, xa_mid + base0, 1.0f);

    // ---- grid barrier (256 block-arrivals, device scope) ----
    __threadfence();          // make mid stores visible device-wide
    __syncthreads();          // all waves of this block done
    if (tid == 0) {
        unsigned arrived = __hip_atomic_fetch_add(
            bar_cnt, 1u, __ATOMIC_ACQ_REL, __HIP_MEMORY_SCOPE_AGENT) + 1;
        if (arrived == (unsigned)kBlocks) {
            __hip_atomic_store(bar_gen, 1u, __ATOMIC_RELEASE,
                               __HIP_MEMORY_SCOPE_AGENT);
        } else {
            while (__hip_atomic_load(bar_gen, __ATOMIC_ACQUIRE,
                                     __HIP_MEMORY_SCOPE_AGENT) == 0u) {
                __builtin_amdgcn_s_sleep(2);
            }
        }
    }
    __syncthreads();
    __threadfence();          // acquire: see other blocks' mid stores

    // ---- layer 1 (s = 1): row = ((g + o) % m)*32 + o ----
    const int r1 = (((g + o) & (kM - 1)) << 5) + o;
    const size_t base1 = ((size_t)(b * kN + r1)) * kE + n * kCE + h * kH;

    LD16S(zi, x_mid + base1, L1);
    LD16S(xa, xa_mid + base1, 1.0f);
    LD16S(wi, W + 2 * kE + n * kCE + h * kH, iL1);
    LD16S(wj, W + 3 * kE + n * kCE + h * kH, iL1);

    SCAN_LAYER();

    ST16S(zi, x_out + base1, iL1);
    ST16S(xa, xa_out + base1, 1.0f);
}

extern "C" void kernel_launch(void* const* d_in, const int* in_sizes, int n_in,
                              void* d_out, int out_size, void* d_ws, size_t ws_size,
                              hipStream_t stream) {
    const float* x  = (const float*)d_in[0];   // [B, N, E] fp32
    const float* xa = (const float*)d_in[1];   // [B, N, E] fp32
    const float* W  = (const float*)d_in[2];   // [2, 256] fp32

    const size_t plane = (size_t)kB * kN * kE;   // 2,097,152 floats

    // ws layout: [0..511] barrier state; mid buffers from offset 1024 B.
    unsigned* bar_cnt = (unsigned*)d_ws;
    unsigned* bar_gen = (unsigned*)((char*)d_ws + 256);
    float* x_mid  = (float*)((char*)d_ws + 1024);
    float* xa_mid = x_mid + plane;

    float* x_out  = (float*)d_out;
    float* xa_out = x_out + plane;

    // zero barrier state (capture-legal async memset; launch stays idempotent)
    hipMemsetAsync(d_ws, 0, 512, stream);

    ncn_fused_kernel<<<dim3(kBlocks), dim3(kThreads), 0, stream>>>(
        x, xa, W, x_mid, xa_mid, x_out, xa_out, bar_cnt, bar_gen);
}

// Round 14
// 240.242 us; speedup vs baseline: 1.0093x; 1.0093x over previous
//
#include <hip/hip_runtime.h>

// NCN recurrence, 2 layers fused into ONE persistent kernel.
// B=4, N=4096, E=128, NK=4, ce=32, CACHE=32, m=128.
// 2048 independent [32x32] subproblems per layer; one WAVE per subproblem.
// Grid 256 blocks x 512 threads (8 waves/block, 1 block/CU co-resident ->
// device-scope atomic grid barrier between layers is deadlock-free).
//
// R14 = R13 + __attribute__((amdgpu_waves_per_eu(2,2))). R10/R13 both showed
// VGPR_Count=52 (allocator TARGETS ~8 waves/EU and spills the ~110-float
// state to scratch; launch_bounds' 2nd arg only sets an occupancy FLOOR so
// it cannot stop that). waves_per_eu(2,2) pins the occupancy assumption to
// exactly the 2 waves/EU the grid supplies -> VGPR budget 256 -> no spill.
// Scratch fits in L2 (0.5MB) which is why the spill showed as latency
// (VALUBusy 15%) not HBM traffic.
//
// State pre-scaled: zi = L1*x (L1=log2 e), weights W/L1:
//   sim = dot32(zi,W/L1-pair); arg = zi + sim*zj  (= 2*L1*T)
// tanh via 0.1F = 0.1 - 0.2/(exp2(arg)+1), unclamped (over/underflow -> +-1).
// Scan step: 16 bpermute zj pulls; u = dot16(zi,wi)+dot16(zj,wj);
// sim = u + shfl_xor(u,32)  (zj uniform per half => Wj term uniform).
// Barrier state in ws[0..511], zeroed by hipMemsetAsync -> idempotent launch.

namespace {
constexpr int kB = 4;
constexpr int kN = 4096;
constexpr int kE = 128;
constexpr int kCE = 32;          // E / NK
constexpr int kH  = 16;          // feats per lane
constexpr int kCache = 32;
constexpr int kM = kN / kCache;  // 128 groups per batch
constexpr int kBlocks = 256;
constexpr int kThreads = 512;    // 8 waves/block

typedef __attribute__((ext_vector_type(2))) float f32x2;

__device__ __forceinline__ f32x2 pk_fma(f32x2 a, f32x2 b, f32x2 c) {
    return __builtin_elementwise_fma(a, b, c);
}
__device__ __forceinline__ float bperm_f(int addr, float v) {
    return __int_as_float(__builtin_amdgcn_ds_bpermute(addr, __float_as_int(v)));
}
}  // namespace

// load 16 floats (4x float4) into 8 named f32x2, scaled by constant sc
#define LD16S(dst, ptr, sc)                                             \
    {                                                                   \
        const float4* p4 = reinterpret_cast<const float4*>(ptr);        \
        float4 q0 = p4[0], q1 = p4[1], q2 = p4[2], q3 = p4[3];          \
        dst##0 = f32x2{q0.x * sc, q0.y * sc};                           \
        dst##1 = f32x2{q0.z * sc, q0.w * sc};                           \
        dst##2 = f32x2{q1.x * sc, q1.y * sc};                           \
        dst##3 = f32x2{q1.z * sc, q1.w * sc};                           \
        dst##4 = f32x2{q2.x * sc, q2.y * sc};                           \
        dst##5 = f32x2{q2.z * sc, q2.w * sc};                           \
        dst##6 = f32x2{q3.x * sc, q3.y * sc};                           \
        dst##7 = f32x2{q3.z * sc, q3.w * sc};                           \
    }

// store 8 named f32x2 as 4x float4, scaled by constant sc
#define ST16S(src, ptr, sc)                                             \
    {                                                                   \
        float4* p4 = reinterpret_cast<float4*>(ptr);                    \
        p4[0] = float4{src##0 .x * sc, src##0 .y * sc,                  \
                       src##1 .x * sc, src##1 .y * sc};                 \
        p4[1] = float4{src##2 .x * sc, src##2 .y * sc,                  \
                       src##3 .x * sc, src##3 .y * sc};                 \
        p4[2] = float4{src##4 .x * sc, src##4 .y * sc,                  \
                       src##5 .x * sc, src##5 .y * sc};                 \
        p4[3] = float4{src##6 .x * sc, src##6 .y * sc,                  \
                       src##7 .x * sc, src##7 .y * sc};                 \
    }

#define PULL(q)                                                         \
    f32x2 zj##q;                                                        \
    zj##q .x = bperm_f(srcaddr, zi##q .x);                              \
    zj##q .y = bperm_f(srcaddr, zi##q .y);

#define UPD(q)                                                          \
    {                                                                   \
        f32x2 arg = pk_fma(zj##q, sv, zi##q);                           \
        f32x2 t2;                                                       \
        t2.x = __builtin_amdgcn_exp2f(arg.x);                           \
        t2.y = __builtin_amdgcn_exp2f(arg.y);                           \
        f32x2 den = t2 + one;                                           \
        f32x2 rc;                                                       \
        rc.x = __builtin_amdgcn_rcpf(den.x);                            \
        rc.y = __builtin_amdgcn_rcpf(den.y);                            \
        xa##q = pk_fma(m02, rc, pk_fma(c9, xa##q, c01));                \
        zi##q = pk_fma(cL1, xa##q, zi##q * c9);                         \
    }

// one layer's 32-step scan on the named state (zi/xa/wi/wj must be in scope)
#define SCAN_LAYER()                                                    \
    _Pragma("unroll 2")                                                 \
    for (int j = 0; j < kCache; ++j) {                                  \
        const int srcaddr = srcbase + j * 4;                            \
        PULL(0) PULL(1) PULL(2) PULL(3) PULL(4) PULL(5) PULL(6) PULL(7) \
        f32x2 A = zi0 * wi0;                                            \
        f32x2 Bv = zi1 * wi1;                                           \
        f32x2 C = zj0 * wj0;                                            \
        f32x2 D = zj1 * wj1;                                            \
        A  = pk_fma(zi2, wi2, A);  Bv = pk_fma(zi3, wi3, Bv);           \
        C  = pk_fma(zj2, wj2, C);  D  = pk_fma(zj3, wj3, D);            \
        A  = pk_fma(zi4, wi4, A);  Bv = pk_fma(zi5, wi5, Bv);           \
        C  = pk_fma(zj4, wj4, C);  D  = pk_fma(zj5, wj5, D);            \
        A  = pk_fma(zi6, wi6, A);  Bv = pk_fma(zi7, wi7, Bv);           \
        C  = pk_fma(zj6, wj6, C);  D  = pk_fma(zj7, wj7, D);            \
        f32x2 uv = (A + Bv) + (C + D);                                  \
        float u  = uv.x + uv.y;                                         \
        const float sim = u + __shfl_xor(u, 32, 64);                    \
        const f32x2 sv = {sim, sim};                                    \
        UPD(0) UPD(1) UPD(2) UPD(3) UPD(4) UPD(5) UPD(6) UPD(7)         \
    }

__global__ void __launch_bounds__(kThreads)
__attribute__((amdgpu_waves_per_eu(2, 2)))
ncn_fused_kernel(
    const float* __restrict__ x_in, const float* __restrict__ xa_in,
    const float* __restrict__ W,    // 2 layers x 256 floats
    float* __restrict__ x_mid, float* __restrict__ xa_mid,
    float* __restrict__ x_out, float* __restrict__ xa_out,
    unsigned* __restrict__ bar_cnt, unsigned* __restrict__ bar_gen)
{
    const int tid  = threadIdx.x;
    const int wave = tid >> 6;
    const int lane = tid & 63;
    const int id   = blockIdx.x * 8 + wave;   // subproblem id, 0..2047
    const int n    = id & 3;
    const int g    = (id >> 2) & (kM - 1);
    const int b    = id >> 9;
    const int o    = lane & 31;
    const int h    = lane >> 5;

    constexpr float L1   = 1.4426950408889634f;   // log2(e)
    constexpr float iL1  = 0.6931471805599453f;   // 1/L1 = ln 2
    const f32x2 one = {1.0f, 1.0f};
    const f32x2 m02 = {-0.2f, -0.2f};
    const f32x2 c9  = {0.9f, 0.9f};
    const f32x2 c01 = {0.1f, 0.1f};
    const f32x2 cL1 = {0.1f * L1, 0.1f * L1};

    const int srcbase = (lane & 32) * 4;   // zj source lane = (lane&32) + j

    f32x2 zi0, zi1, zi2, zi3, zi4, zi5, zi6, zi7;
    f32x2 xa0, xa1, xa2, xa3, xa4, xa5, xa6, xa7;
    f32x2 wi0, wi1, wi2, wi3, wi4, wi5, wi6, wi7;
    f32x2 wj0, wj1, wj2, wj3, wj4, wj5, wj6, wj7;

    // ---- layer 0 (s = 0): row = g*32 + o ----
    const int r0 = (g << 5) + o;
    const size_t base0 = ((size_t)(b * kN + r0)) * kE + n * kCE + h * kH;

    LD16S(zi, x_in + base0, L1);
    LD16S(xa, xa_in + base0, 1.0f);
    LD16S(wi, W + n * kCE + h * kH, iL1);
    LD16S(wj, W + kE + n * kCE + h * kH, iL1);

    SCAN_LAYER();

    ST16S(zi, x_mid + base0, iL1);
    ST16S(xa, xa_mid + base0, 1.0f);

    // ---- grid barrier (256 block-arrivals, device scope) ----
    __threadfence();          // make mid stores visible device-wide
    __syncthreads();          // all waves of this block done
    if (tid == 0) {
        unsigned arrived = __hip_atomic_fetch_add(
            bar_cnt, 1u, __ATOMIC_ACQ_REL, __HIP_MEMORY_SCOPE_AGENT) + 1;
        if (arrived == (unsigned)kBlocks) {
            __hip_atomic_store(bar_gen, 1u, __ATOMIC_RELEASE,
                               __HIP_MEMORY_SCOPE_AGENT);
        } else {
            while (__hip_atomic_load(bar_gen, __ATOMIC_ACQUIRE,
                                     __HIP_MEMORY_SCOPE_AGENT) == 0u) {
                __builtin_amdgcn_s_sleep(2);
            }
        }
    }
    __syncthreads();
    __threadfence();          // acquire: see other blocks' mid stores

    // ---- layer 1 (s = 1): row = ((g + o) % m)*32 + o ----
    const int r1 = (((g + o) & (kM - 1)) << 5) + o;
    const size_t base1 = ((size_t)(b * kN + r1)) * kE + n * kCE + h * kH;

    LD16S(zi, x_mid + base1, L1);
    LD16S(xa, xa_mid + base1, 1.0f);
    LD16S(wi, W + 2 * kE + n * kCE + h * kH, iL1);
    LD16S(wj, W + 3 * kE + n * kCE + h * kH, iL1);

    SCAN_LAYER();

    ST16S(zi, x_out + base1, iL1);
    ST16S(xa, xa_out + base1, 1.0f);
}

extern "C" void kernel_launch(void* const* d_in, const int* in_sizes, int n_in,
                              void* d_out, int out_size, void* d_ws, size_t ws_size,
                              hipStream_t stream) {
    const float* x  = (const float*)d_in[0];   // [B, N, E] fp32
    const float* xa = (const float*)d_in[1];   // [B, N, E] fp32
    const float* W  = (const float*)d_in[2];   // [2, 256] fp32

    const size_t plane = (size_t)kB * kN * kE;   // 2,097,152 floats

    // ws layout: [0..511] barrier state; mid buffers from offset 1024 B.
    unsigned* bar_cnt = (unsigned*)d_ws;
    unsigned* bar_gen = (unsigned*)((char*)d_ws + 256);
    float* x_mid  = (float*)((char*)d_ws + 1024);
    float* xa_mid = x_mid + plane;

    float* x_out  = (float*)d_out;
    float* xa_out = x_out + plane;

    // zero barrier state (capture-legal async memset; launch stays idempotent)
    hipMemsetAsync(d_ws, 0, 512, stream);

    ncn_fused_kernel<<<dim3(kBlocks), dim3(kThreads), 0, stream>>>(
        x, xa, W, x_mid, xa_mid, x_out, xa_out, bar_cnt, bar_gen);
}